// Round 2
// baseline (309.964 us; speedup 1.0000x reference)
//
#include <hip/hip_runtime.h>
#include <math.h>

#define B_  32
#define S_  4096
#define E_  256
#define A_  256
#define DE_ 512

typedef __attribute__((ext_vector_type(8))) short short8;
typedef __attribute__((ext_vector_type(4))) float f32x4;

__device__ inline unsigned short f2bf(float x) {
    unsigned int u = __float_as_uint(x);
    u += 0x7FFFu + ((u >> 16) & 1u);      // round-to-nearest-even
    return (unsigned short)(u >> 16);
}
__device__ inline float tanh_fast(float x) {
    x = fminf(fmaxf(x, -15.f), 15.f);
    float t = __expf(2.f * x);
    return (t - 1.f) * __builtin_amdgcn_rcpf(t + 1.f);
}

// ---- Prep: block 0..63 = pack We hi/lo bf16 (fragment order),
//            block 64..95 = proj, block 96 = zero attended region.
__global__ __launch_bounds__(256) void prep_kernel(
    const float* __restrict__ W, const float* __restrict__ dh,
    const float* __restrict__ bias, unsigned short* __restrict__ wepk,
    float* __restrict__ proj, float* __restrict__ out)
{
    __shared__ float dh_lds[E_];
    const int bk  = blockIdx.x;
    const int tid = threadIdx.x;
    if (bk < 64) {
        // unit = c*2048 + plane*1024 + kg*256 + a; 8 bf16 = We[a][c*32+kg*8..+8]
        const int idx = bk * 256 + tid;
        const int c     = idx >> 11;
        const int r     = idx & 2047;
        const int plane = r >> 10;
        const int kg    = (r >> 8) & 3;
        const int a     = r & 255;
        const float* src = W + (size_t)a * DE_ + E_ + c * 32 + kg * 8;
        unsigned int pk[4];
        #pragma unroll
        for (int j = 0; j < 4; ++j) {
            float x0 = src[2 * j], x1 = src[2 * j + 1];
            unsigned int u0 = __float_as_uint(x0) & 0xFFFF0000u;
            unsigned int u1 = __float_as_uint(x1) & 0xFFFF0000u;
            if (plane) {
                unsigned short l0 = f2bf(x0 - __uint_as_float(u0));
                unsigned short l1 = f2bf(x1 - __uint_as_float(u1));
                pk[j] = (unsigned int)l0 | ((unsigned int)l1 << 16);
            } else {
                pk[j] = (u0 >> 16) | u1;
            }
        }
        *(uint4*)&wepk[(size_t)idx * 8] = make_uint4(pk[0], pk[1], pk[2], pk[3]);
    } else if (bk < 96) {
        const int b = bk - 64;
        const int a = tid;
        dh_lds[a] = dh[b * E_ + a];
        __syncthreads();
        float acc = bias[a];
        const float* wrow = W + (size_t)a * DE_;
        #pragma unroll
        for (int d = 0; d < E_; d += 4) {
            float4 w = *(const float4*)(wrow + d);
            acc += dh_lds[d] * w.x + dh_lds[d+1] * w.y
                 + dh_lds[d+2] * w.z + dh_lds[d+3] * w.w;
        }
        proj[b * A_ + a] = acc;
    } else {
        #pragma unroll
        for (int j = tid; j < B_ * E_; j += 256) out[j] = 0.f;
    }
}

// ---- Scores v4: TS=64 s-rows/block (2048 blocks), wave = 64s x 64a.
// acc halves to 64 AGPRs -> __launch_bounds__(256,4) targets 4 waves/SIMD
// (16 waves/CU, 2x occupancy). We fragments global->reg (L2-hot).
// eo LDS layout: unit = plane*264 + kg*66 + row (66 % 8 == 2 -> b128
// writes & reads conflict-free, same bank arithmetic as the 130 stride).
__global__ __launch_bounds__(256, 4) void scores_kernel(
    const float* __restrict__ eo, const unsigned short* __restrict__ wepk,
    const float* __restrict__ proj,
    float* __restrict__ scores, float* __restrict__ nsq)
{
    // main phase: eo_hl [0,8448)
    // epilogue overlay: red4 [64][66] floats @0; npart @16896; qpart @17920
    __shared__ __align__(16) unsigned char pool[18944];
    unsigned short* eo_hl = (unsigned short*)pool;

    const int tid = threadIdx.x;
    const int b   = blockIdx.x & (B_ - 1);
    const int s0  = (blockIdx.x >> 5) * 64;
    const int w   = tid >> 6, l = tid & 63;   // w = a-block of this wave
    const int lq  = l >> 4,  lr = l & 15;

    // eo staging map: 4 lanes per row, lane covers one kg (8 floats, 32 B)
    const int erow = tid >> 2;          // 0..63
    const int ekg  = tid & 3;
    const float* ebase = eo + (size_t)(s0 + erow) * (B_ * E_) + b * E_ + ekg * 8;

    // We fragment unit (16B units): c*2048 + plane*1024 + lq*256 + (w*64+nt*16+lr)
    const int wunit = lq * 256 + w * 64 + lr;

    f32x4 acc[4][4];
    #pragma unroll
    for (int i = 0; i < 4; ++i)
        #pragma unroll
        for (int j = 0; j < 4; ++j)
            acc[i][j] = (f32x4){0.f, 0.f, 0.f, 0.f};
    float nacc = 0.f;

    // prologue: prefetch chunk-0 eo into registers
    float4 ea0 = *(const float4*)(ebase);
    float4 ea1 = *(const float4*)(ebase + 4);

    for (int c = 0; c < 8; ++c) {
        __syncthreads();   // prev compute's ds_reads done; LDS reusable
        // ---- issue We fragment loads for chunk c (global -> regs, L2-hot);
        // in flight through the convert phase below.
        short8 bh[4], bl[4];
        {
            const unsigned short* wsrc = wepk + (size_t)(c * 2048 + wunit) * 8;
            #pragma unroll
            for (int nt = 0; nt < 4; ++nt) {
                bh[nt] = *(const short8*)(wsrc + (size_t)(nt * 16) * 8);
                bl[nt] = *(const short8*)(wsrc + (size_t)(1024 + nt * 16) * 8);
            }
        }
        // ---- convert + ds_write eo chunk c (b128, conflict-free)
        {
            float4 v0 = ea0;
            float4 v1 = ea1;
            nacc += v0.x*v0.x + v0.y*v0.y + v0.z*v0.z + v0.w*v0.w
                  + v1.x*v1.x + v1.y*v1.y + v1.z*v1.z + v1.w*v1.w;
            float xs[8] = {v0.x, v0.y, v0.z, v0.w, v1.x, v1.y, v1.z, v1.w};
            unsigned int hp[4], lp[4];
            #pragma unroll
            for (int j = 0; j < 4; ++j) {
                unsigned int u0 = __float_as_uint(xs[2*j])   & 0xFFFF0000u;
                unsigned int u1 = __float_as_uint(xs[2*j+1]) & 0xFFFF0000u;
                hp[j] = (u0 >> 16) | u1;
                lp[j] = (unsigned int)f2bf(xs[2*j]   - __uint_as_float(u0))
                      | ((unsigned int)f2bf(xs[2*j+1] - __uint_as_float(u1)) << 16);
            }
            const int u = ekg * 66 + erow;
            *(uint4*)&eo_hl[(size_t)u * 8]         = make_uint4(hp[0], hp[1], hp[2], hp[3]);
            *(uint4*)&eo_hl[(size_t)(264 + u) * 8] = make_uint4(lp[0], lp[1], lp[2], lp[3]);
        }
        __syncthreads();   // eo writes visible (lgkm only)
        if (c < 7) {       // prefetch next eo AFTER the barrier: in flight through MFMAs
            ea0 = *(const float4*)(ebase + (c + 1) * 32);
            ea1 = *(const float4*)(ebase + (c + 1) * 32 + 4);
        }
        // ---- compute chunk c: 48 MFMA per wave
        #pragma unroll
        for (int mt = 0; mt < 4; ++mt) {
            const int au = lq * 66 + mt * 16 + lr;
            short8 ah = *(const short8*)&eo_hl[(size_t)au * 8];
            short8 al = *(const short8*)&eo_hl[(size_t)(264 + au) * 8];
            #pragma unroll
            for (int nt = 0; nt < 4; ++nt) {
                acc[mt][nt] = __builtin_amdgcn_mfma_f32_16x16x32_bf16(ah, bh[nt], acc[mt][nt], 0, 0, 0);
                acc[mt][nt] = __builtin_amdgcn_mfma_f32_16x16x32_bf16(ah, bl[nt], acc[mt][nt], 0, 0, 0);
                acc[mt][nt] = __builtin_amdgcn_mfma_f32_16x16x32_bf16(al, bh[nt], acc[mt][nt], 0, 0, 0);
            }
        }
    }
    __syncthreads();   // all fragment reads done before LDS overlay

    // ---- epilogue: tanh + reduce over a
    float* red4  = (float*)pool;                 // [64 a-groups][66] floats
    float* npart = (float*)(pool + 16896);       // 256 floats
    float* qpart = (float*)(pool + 17920);       // 256 floats
    float pr[4];
    #pragma unroll
    for (int nt = 0; nt < 4; ++nt) pr[nt] = proj[b * A_ + w * 64 + nt * 16 + lr];
    #pragma unroll
    for (int mt = 0; mt < 4; ++mt) {
        #pragma unroll
        for (int r = 0; r < 4; ++r) {
            float s = 0.f;
            #pragma unroll
            for (int nt = 0; nt < 4; ++nt)
                s += tanh_fast(pr[nt] + acc[mt][nt][r]);
            // C/D layout: col = lr (a-dim), row = mt*16 + lq*4 + r (s-dim)
            red4[(w * 16 + lr) * 66 + (mt * 16 + lq * 4 + r)] = s;
        }
    }
    npart[tid] = nacc;    // partial (1/4 of E) of row tid>>2
    __syncthreads();
    {   // 256 threads: (row = tid>>2, quarter = tid&3) sums 16 of 64 a-groups
        const int row = tid >> 2, quarter = tid & 3;
        float s = 0.f;
        #pragma unroll
        for (int j = 0; j < 16; ++j) s += red4[(quarter * 16 + j) * 66 + row];
        qpart[quarter * 64 + row] = s;
    }
    __syncthreads();
    if (tid < 64) {
        scores[b * S_ + s0 + tid] = qpart[tid] + qpart[64 + tid]
                                  + qpart[128 + tid] + qpart[192 + tid];
        nsq[b * S_ + s0 + tid] = npart[4 * tid] + npart[4 * tid + 1]
                               + npart[4 * tid + 2] + npart[4 * tid + 3];
    }
}

// ---- Stats: per-b softmax stats computed ONCE (not per attend block).
// Writes attn_map, and overwrites nsq[] in-place with normalized probs
// (each element read-then-written only by its owner thread — race-free).
__global__ __launch_bounds__(256) void stats_kernel(
    const float* __restrict__ scores, float* __restrict__ nsq_pv,
    float* __restrict__ out)
{
    __shared__ float red[256];
    const int tid  = threadIdx.x;
    const int b    = blockIdx.x & (B_ - 1);
    const int part = blockIdx.x >> 5;      // 0..7: which 512-slice this block writes
    float v[16];
    float m = -1e30f;
    #pragma unroll
    for (int i = 0; i < 16; ++i) {
        v[i] = scores[b * S_ + i * 256 + tid];
        m = fmaxf(m, v[i]);
    }
    red[tid] = m;
    __syncthreads();
    for (int off = 128; off > 0; off >>= 1) {
        if (tid < off) red[tid] = fmaxf(red[tid], red[tid + off]);
        __syncthreads();
    }
    m = red[0];
    __syncthreads();
    float sum = 0.f;
    #pragma unroll
    for (int i = 0; i < 16; ++i) sum += __expf(v[i] - m);
    red[tid] = sum;
    __syncthreads();
    for (int off = 128; off > 0; off >>= 1) {
        if (tid < off) red[tid] += red[tid + off];
        __syncthreads();
    }
    const float inv = 1.f / red[0];
    #pragma unroll
    for (int j = 0; j < 2; ++j) {
        const int i = part * 2 + j;
        const int s = i * 256 + tid;
        const float pv = __expf(v[i] - m) * inv;
        out[B_ * E_ + b * S_ + s] = pv * sqrtf(nsq_pv[b * S_ + s]);
        nsq_pv[b * S_ + s] = pv;
    }
}

// ---- Attend: pure-bandwidth accumulation (no softmax recompute).
__global__ __launch_bounds__(256) void attend_kernel(
    const float* __restrict__ eo, const float* __restrict__ pv,
    float* __restrict__ out)
{
    __shared__ float4 acc_red[4][64];
    const int tid = threadIdx.x;
    const int b   = blockIdx.x & (B_ - 1);
    const int ch  = blockIdx.x / B_;
    const int le = tid & 63, sg = tid >> 6;
    const int s0 = ch * 128 + sg * 32;
    float4 a = make_float4(0.f, 0.f, 0.f, 0.f);
    #pragma unroll 8
    for (int s = 0; s < 32; ++s) {
        float p = pv[b * S_ + s0 + s];
        float4 e = *(const float4*)(eo + (size_t)(s0 + s) * (B_ * E_)
                                       + b * E_ + le * 4);
        a.x = fmaf(p, e.x, a.x);
        a.y = fmaf(p, e.y, a.y);
        a.z = fmaf(p, e.z, a.z);
        a.w = fmaf(p, e.w, a.w);
    }
    acc_red[sg][le] = a;
    __syncthreads();
    if (tid < 64) {
        float4 a0 = acc_red[0][tid], a1 = acc_red[1][tid];
        float4 a2 = acc_red[2][tid], a3 = acc_red[3][tid];
        float* dst = out + b * E_ + tid * 4;
        atomicAdd(dst + 0, a0.x + a1.x + a2.x + a3.x);
        atomicAdd(dst + 1, a0.y + a1.y + a2.y + a3.y);
        atomicAdd(dst + 2, a0.z + a1.z + a2.z + a3.z);
        atomicAdd(dst + 3, a0.w + a1.w + a2.w + a3.w);
    }
}

extern "C" void kernel_launch(void* const* d_in, const int* in_sizes, int n_in,
                              void* d_out, int out_size, void* d_ws, size_t ws_size,
                              hipStream_t stream)
{
    const float* dh   = (const float*)d_in[0];  // (1,B,D)
    const float* eo   = (const float*)d_in[1];  // (S,B,E)
    const float* W    = (const float*)d_in[2];  // (A, D+E)
    const float* bias = (const float*)d_in[3];  // (A,)
    float* out = (float*)d_out;                 // [attended 8192 | attn_map 131072]
    float* ws  = (float*)d_ws;

    float* projb  = ws;                           // 8192 floats
    float* nsqb   = ws + 8192;                    // 131072 floats (nsq, then pv in-place)
    float* scores = nsqb + S_ * B_;               // 131072 floats
    unsigned short* wepk = (unsigned short*)(scores + S_ * B_);  // 256 KB packed We

    prep_kernel   <<<97,              256, 0, stream>>>(W, dh, bias, wepk, projb, out);
    scores_kernel <<<B_ * (S_ / 64),  256, 0, stream>>>(eo, wepk, projb, scores, nsqb);
    stats_kernel  <<<B_ * 8,          256, 0, stream>>>(scores, nsqb, out);
    attend_kernel <<<B_ * (S_ / 128), 256, 0, stream>>>(eo, nsqb, out);
}

// Round 3
// 256.845 us; speedup vs baseline: 1.2068x; 1.2068x over previous
//
#include <hip/hip_runtime.h>
#include <math.h>

#define B_  32
#define S_  4096
#define E_  256
#define A_  256
#define DE_ 512

typedef __attribute__((ext_vector_type(8))) short short8;
typedef __attribute__((ext_vector_type(4))) float f32x4;

__device__ inline unsigned short f2bf(float x) {
    unsigned int u = __float_as_uint(x);
    u += 0x7FFFu + ((u >> 16) & 1u);      // round-to-nearest-even
    return (unsigned short)(u >> 16);
}
__device__ inline float tanh_fast(float x) {
    x = fminf(fmaxf(x, -15.f), 15.f);
    float t = __expf(2.f * x);
    return (t - 1.f) * __builtin_amdgcn_rcpf(t + 1.f);
}

// ---- Prep: block 0..63 = pack We hi/lo bf16 (fragment order),
//            block 64..95 = proj, block 96 = zero attended region.
__global__ __launch_bounds__(256) void prep_kernel(
    const float* __restrict__ W, const float* __restrict__ dh,
    const float* __restrict__ bias, unsigned short* __restrict__ wepk,
    float* __restrict__ proj, float* __restrict__ out)
{
    __shared__ float dh_lds[E_];
    const int bk  = blockIdx.x;
    const int tid = threadIdx.x;
    if (bk < 64) {
        // unit = c*2048 + plane*1024 + kg*256 + a; 8 bf16 = We[a][c*32+kg*8..+8]
        const int idx = bk * 256 + tid;
        const int c     = idx >> 11;
        const int r     = idx & 2047;
        const int plane = r >> 10;
        const int kg    = (r >> 8) & 3;
        const int a     = r & 255;
        const float* src = W + (size_t)a * DE_ + E_ + c * 32 + kg * 8;
        unsigned int pk[4];
        #pragma unroll
        for (int j = 0; j < 4; ++j) {
            float x0 = src[2 * j], x1 = src[2 * j + 1];
            unsigned int u0 = __float_as_uint(x0) & 0xFFFF0000u;
            unsigned int u1 = __float_as_uint(x1) & 0xFFFF0000u;
            if (plane) {
                unsigned short l0 = f2bf(x0 - __uint_as_float(u0));
                unsigned short l1 = f2bf(x1 - __uint_as_float(u1));
                pk[j] = (unsigned int)l0 | ((unsigned int)l1 << 16);
            } else {
                pk[j] = (u0 >> 16) | u1;
            }
        }
        *(uint4*)&wepk[(size_t)idx * 8] = make_uint4(pk[0], pk[1], pk[2], pk[3]);
    } else if (bk < 96) {
        const int b = bk - 64;
        const int a = tid;
        dh_lds[a] = dh[b * E_ + a];
        __syncthreads();
        float acc = bias[a];
        const float* wrow = W + (size_t)a * DE_;
        #pragma unroll
        for (int d = 0; d < E_; d += 4) {
            float4 w = *(const float4*)(wrow + d);
            acc += dh_lds[d] * w.x + dh_lds[d+1] * w.y
                 + dh_lds[d+2] * w.z + dh_lds[d+3] * w.w;
        }
        proj[b * A_ + a] = acc;
    } else {
        #pragma unroll
        for (int j = tid; j < B_ * E_; j += 256) out[j] = 0.f;
    }
}

// ---- Scores v5: TS=64 s-rows/block (2048 blocks), wave = 64s x 64a.
// acc = 64 AGPRs. Budget arithmetic: 3 waves/SIMD needs <= 170 regs/wave;
// 64 acc + ~100 arch fits. R2's (256,4) cap (128 regs) caused 200 MB of
// scratch spill -> (256,3) here. We fragments global->reg (L2-hot).
// eo LDS: unit = plane*264 + kg*66 + row (66 % 8 == 2 -> b128 conflict-free).
__global__ __launch_bounds__(256, 3) void scores_kernel(
    const float* __restrict__ eo, const unsigned short* __restrict__ wepk,
    const float* __restrict__ proj,
    float* __restrict__ scores, float* __restrict__ nsq)
{
    // main phase: eo_hl [0,8448)
    // epilogue overlay: red4 [64][66] floats @0; npart @16896; qpart @17920
    __shared__ __align__(16) unsigned char pool[18944];
    unsigned short* eo_hl = (unsigned short*)pool;

    const int tid = threadIdx.x;
    const int b   = blockIdx.x & (B_ - 1);
    const int s0  = (blockIdx.x >> 5) * 64;
    const int w   = tid >> 6, l = tid & 63;   // w = a-block of this wave
    const int lq  = l >> 4,  lr = l & 15;

    // eo staging map: 4 lanes per row, lane covers one kg (8 floats, 32 B)
    const int erow = tid >> 2;          // 0..63
    const int ekg  = tid & 3;
    const float* ebase = eo + (size_t)(s0 + erow) * (B_ * E_) + b * E_ + ekg * 8;

    // We fragment unit (16B units): c*2048 + plane*1024 + lq*256 + (w*64+nt*16+lr)
    const int wunit = lq * 256 + w * 64 + lr;

    f32x4 acc[4][4];
    #pragma unroll
    for (int i = 0; i < 4; ++i)
        #pragma unroll
        for (int j = 0; j < 4; ++j)
            acc[i][j] = (f32x4){0.f, 0.f, 0.f, 0.f};
    float nacc = 0.f;

    // prologue: prefetch chunk-0 eo into registers
    float4 ea0 = *(const float4*)(ebase);
    float4 ea1 = *(const float4*)(ebase + 4);

    for (int c = 0; c < 8; ++c) {
        __syncthreads();   // prev compute's ds_reads done; LDS reusable
        // ---- issue We fragment loads for chunk c (global -> regs, L2-hot);
        // in flight through the convert phase below.
        short8 bh[4], bl[4];
        {
            const unsigned short* wsrc = wepk + (size_t)(c * 2048 + wunit) * 8;
            #pragma unroll
            for (int nt = 0; nt < 4; ++nt) {
                bh[nt] = *(const short8*)(wsrc + (size_t)(nt * 16) * 8);
                bl[nt] = *(const short8*)(wsrc + (size_t)(1024 + nt * 16) * 8);
            }
        }
        // ---- convert + ds_write eo chunk c (b128, conflict-free)
        {
            float4 v0 = ea0;
            float4 v1 = ea1;
            nacc += v0.x*v0.x + v0.y*v0.y + v0.z*v0.z + v0.w*v0.w
                  + v1.x*v1.x + v1.y*v1.y + v1.z*v1.z + v1.w*v1.w;
            float xs[8] = {v0.x, v0.y, v0.z, v0.w, v1.x, v1.y, v1.z, v1.w};
            unsigned int hp[4], lp[4];
            #pragma unroll
            for (int j = 0; j < 4; ++j) {
                unsigned int u0 = __float_as_uint(xs[2*j])   & 0xFFFF0000u;
                unsigned int u1 = __float_as_uint(xs[2*j+1]) & 0xFFFF0000u;
                hp[j] = (u0 >> 16) | u1;
                lp[j] = (unsigned int)f2bf(xs[2*j]   - __uint_as_float(u0))
                      | ((unsigned int)f2bf(xs[2*j+1] - __uint_as_float(u1)) << 16);
            }
            const int u = ekg * 66 + erow;
            *(uint4*)&eo_hl[(size_t)u * 8]         = make_uint4(hp[0], hp[1], hp[2], hp[3]);
            *(uint4*)&eo_hl[(size_t)(264 + u) * 8] = make_uint4(lp[0], lp[1], lp[2], lp[3]);
        }
        __syncthreads();   // eo writes visible (lgkm only)
        if (c < 7) {       // prefetch next eo AFTER the barrier: in flight through MFMAs
            ea0 = *(const float4*)(ebase + (c + 1) * 32);
            ea1 = *(const float4*)(ebase + (c + 1) * 32 + 4);
        }
        // ---- compute chunk c: 48 MFMA per wave
        #pragma unroll
        for (int mt = 0; mt < 4; ++mt) {
            const int au = lq * 66 + mt * 16 + lr;
            short8 ah = *(const short8*)&eo_hl[(size_t)au * 8];
            short8 al = *(const short8*)&eo_hl[(size_t)(264 + au) * 8];
            #pragma unroll
            for (int nt = 0; nt < 4; ++nt) {
                acc[mt][nt] = __builtin_amdgcn_mfma_f32_16x16x32_bf16(ah, bh[nt], acc[mt][nt], 0, 0, 0);
                acc[mt][nt] = __builtin_amdgcn_mfma_f32_16x16x32_bf16(ah, bl[nt], acc[mt][nt], 0, 0, 0);
                acc[mt][nt] = __builtin_amdgcn_mfma_f32_16x16x32_bf16(al, bh[nt], acc[mt][nt], 0, 0, 0);
            }
        }
    }
    __syncthreads();   // all fragment reads done before LDS overlay

    // ---- epilogue: tanh + reduce over a
    float* red4  = (float*)pool;                 // [64 a-groups][66] floats
    float* npart = (float*)(pool + 16896);       // 256 floats
    float* qpart = (float*)(pool + 17920);       // 256 floats
    float pr[4];
    #pragma unroll
    for (int nt = 0; nt < 4; ++nt) pr[nt] = proj[b * A_ + w * 64 + nt * 16 + lr];
    #pragma unroll
    for (int mt = 0; mt < 4; ++mt) {
        #pragma unroll
        for (int r = 0; r < 4; ++r) {
            float s = 0.f;
            #pragma unroll
            for (int nt = 0; nt < 4; ++nt)
                s += tanh_fast(pr[nt] + acc[mt][nt][r]);
            // C/D layout: col = lr (a-dim), row = mt*16 + lq*4 + r (s-dim)
            red4[(w * 16 + lr) * 66 + (mt * 16 + lq * 4 + r)] = s;
        }
    }
    npart[tid] = nacc;    // partial (1/4 of E) of row tid>>2
    __syncthreads();
    {   // 256 threads: (row = tid>>2, quarter = tid&3) sums 16 of 64 a-groups
        const int row = tid >> 2, quarter = tid & 3;
        float s = 0.f;
        #pragma unroll
        for (int j = 0; j < 16; ++j) s += red4[(quarter * 16 + j) * 66 + row];
        qpart[quarter * 64 + row] = s;
    }
    __syncthreads();
    if (tid < 64) {
        scores[b * S_ + s0 + tid] = qpart[tid] + qpart[64 + tid]
                                  + qpart[128 + tid] + qpart[192 + tid];
        nsq[b * S_ + s0 + tid] = npart[4 * tid] + npart[4 * tid + 1]
                               + npart[4 * tid + 2] + npart[4 * tid + 3];
    }
}

// ---- Stats: per-b softmax stats computed ONCE (not per attend block).
// Writes attn_map, and overwrites nsq[] in-place with normalized probs
// (each element read-then-written only by its owner thread — race-free).
__global__ __launch_bounds__(256) void stats_kernel(
    const float* __restrict__ scores, float* __restrict__ nsq_pv,
    float* __restrict__ out)
{
    __shared__ float red[256];
    const int tid  = threadIdx.x;
    const int b    = blockIdx.x & (B_ - 1);
    const int part = blockIdx.x >> 5;      // 0..7: which 512-slice this block writes
    float v[16];
    float m = -1e30f;
    #pragma unroll
    for (int i = 0; i < 16; ++i) {
        v[i] = scores[b * S_ + i * 256 + tid];
        m = fmaxf(m, v[i]);
    }
    red[tid] = m;
    __syncthreads();
    for (int off = 128; off > 0; off >>= 1) {
        if (tid < off) red[tid] = fmaxf(red[tid], red[tid + off]);
        __syncthreads();
    }
    m = red[0];
    __syncthreads();
    float sum = 0.f;
    #pragma unroll
    for (int i = 0; i < 16; ++i) sum += __expf(v[i] - m);
    red[tid] = sum;
    __syncthreads();
    for (int off = 128; off > 0; off >>= 1) {
        if (tid < off) red[tid] += red[tid + off];
        __syncthreads();
    }
    const float inv = 1.f / red[0];
    #pragma unroll
    for (int j = 0; j < 2; ++j) {
        const int i = part * 2 + j;
        const int s = i * 256 + tid;
        const float pv = __expf(v[i] - m) * inv;
        out[B_ * E_ + b * S_ + s] = pv * sqrtf(nsq_pv[b * S_ + s]);
        nsq_pv[b * S_ + s] = pv;
    }
}

// ---- Attend: pure-bandwidth accumulation (no softmax recompute).
__global__ __launch_bounds__(256) void attend_kernel(
    const float* __restrict__ eo, const float* __restrict__ pv,
    float* __restrict__ out)
{
    __shared__ float4 acc_red[4][64];
    const int tid = threadIdx.x;
    const int b   = blockIdx.x & (B_ - 1);
    const int ch  = blockIdx.x / B_;
    const int le = tid & 63, sg = tid >> 6;
    const int s0 = ch * 128 + sg * 32;
    float4 a = make_float4(0.f, 0.f, 0.f, 0.f);
    #pragma unroll 8
    for (int s = 0; s < 32; ++s) {
        float p = pv[b * S_ + s0 + s];
        float4 e = *(const float4*)(eo + (size_t)(s0 + s) * (B_ * E_)
                                       + b * E_ + le * 4);
        a.x = fmaf(p, e.x, a.x);
        a.y = fmaf(p, e.y, a.y);
        a.z = fmaf(p, e.z, a.z);
        a.w = fmaf(p, e.w, a.w);
    }
    acc_red[sg][le] = a;
    __syncthreads();
    if (tid < 64) {
        float4 a0 = acc_red[0][tid], a1 = acc_red[1][tid];
        float4 a2 = acc_red[2][tid], a3 = acc_red[3][tid];
        float* dst = out + b * E_ + tid * 4;
        atomicAdd(dst + 0, a0.x + a1.x + a2.x + a3.x);
        atomicAdd(dst + 1, a0.y + a1.y + a2.y + a3.y);
        atomicAdd(dst + 2, a0.z + a1.z + a2.z + a3.z);
        atomicAdd(dst + 3, a0.w + a1.w + a2.w + a3.w);
    }
}

extern "C" void kernel_launch(void* const* d_in, const int* in_sizes, int n_in,
                              void* d_out, int out_size, void* d_ws, size_t ws_size,
                              hipStream_t stream)
{
    const float* dh   = (const float*)d_in[0];  // (1,B,D)
    const float* eo   = (const float*)d_in[1];  // (S,B,E)
    const float* W    = (const float*)d_in[2];  // (A, D+E)
    const float* bias = (const float*)d_in[3];  // (A,)
    float* out = (float*)d_out;                 // [attended 8192 | attn_map 131072]
    float* ws  = (float*)d_ws;

    float* projb  = ws;                           // 8192 floats
    float* nsqb   = ws + 8192;                    // 131072 floats (nsq, then pv in-place)
    float* scores = nsqb + S_ * B_;               // 131072 floats
    unsigned short* wepk = (unsigned short*)(scores + S_ * B_);  // 256 KB packed We

    prep_kernel   <<<97,              256, 0, stream>>>(W, dh, bias, wepk, projb, out);
    scores_kernel <<<B_ * (S_ / 64),  256, 0, stream>>>(eo, wepk, projb, scores, nsqb);
    stats_kernel  <<<B_ * 8,          256, 0, stream>>>(scores, nsqb, out);
    attend_kernel <<<B_ * (S_ / 128), 256, 0, stream>>>(eo, nsqb, out);
}